// Round 5
// baseline (589.109 us; speedup 1.0000x reference)
//
#include <hip/hip_runtime.h>

typedef float f4v __attribute__((ext_vector_type(4)));

namespace {
constexpr int Bn = 4, Cn = 32, Dn = 48, Hn = 64, Wn = 128;
constexpr int HQ = 32, WQ = 64;
constexpr int NPB = Dn * HQ * WQ;   // 98304 pooled positions / batch
constexpr int DHW = Dn * Hn * Wn;   // 393216
constexpr int PERB = Cn * DHW;      // 12582912 elements / batch
constexpr int NS = 128, En = 12;
constexpr float EPS = 1e-5f;
constexpr float SQK = 0.2886751345948129f;  // 1/sqrt(12)
constexpr int NBLK = 384;                   // grid.x of big kernels

// workspace float offsets
constexpr size_t OFF_ZB  = 0;                      // bf16[4*32*98304] -> 6291456 floats
constexpr size_t OFF_QR  = 6291456;                // bf16[4*12*98304] -> 2359296 floats
constexpr size_t OFF_P1  = OFF_QR + 2359296;       // float2[4*384] -> 3072 floats
constexpr size_t OFF_P2  = OFF_P1 + 3072;          // float2[4*384] -> 3072 floats
constexpr size_t OFF_ST1 = OFF_P2 + 3072;          // float2[4]
constexpr size_t OFF_ST2 = OFF_ST1 + 8;            // float2[4]
constexpr size_t OFF_PKV = OFF_ST2 + 8;            // 4*4*128*24 = 49152
constexpr size_t OFF_CNT = OFF_PKV + 49152;        // 2 uints
}  // namespace

__device__ inline unsigned short bf16b(float x) {
    unsigned u = __float_as_uint(x);
    return (unsigned short)((u + 0x7fffu + ((u >> 16) & 1u)) >> 16);
}
__device__ inline float b2f(unsigned short h) { return __uint_as_float(((unsigned)h) << 16); }
__device__ inline float bf16_rne(float x) {
    unsigned u = __float_as_uint(x);
    u = (u + 0x7fffu + ((u >> 16) & 1u)) & 0xffff0000u;
    return __uint_as_float(u);
}

// block = 256 threads. Safe for repeated calls (leading barrier protects reuse).
__device__ inline float2 block_red2(float s, float ss) {
#pragma unroll
    for (int off = 32; off; off >>= 1) {
        s += __shfl_down(s, off, 64);
        ss += __shfl_down(ss, off, 64);
    }
    __shared__ float red[8];
    int lane = threadIdx.x & 63, w = threadIdx.x >> 6;
    __syncthreads();
    if (!lane) { red[w] = s; red[4 + w] = ss; }
    __syncthreads();
    return make_float2(red[0] + red[1] + red[2] + red[3],
                       red[4] + red[5] + red[6] + red[7]);
}

// ---------- K0: K/V partials by channel-group; zero the counters ----------
__global__ __launch_bounds__(128) void k_kv(const float* __restrict__ feat,
                                            const float* __restrict__ w_k,
                                            const float* __restrict__ w_v,
                                            float* __restrict__ pkv,
                                            unsigned* __restrict__ cnt) {
    const int g = blockIdx.x;   // kb = g>>2, cg = g&3
    const int s = threadIdx.x;  // key index
    if (g == 0 && s < 2) cnt[s] = 0;
    const int kb = g >> 2, cg = g & 3;
    float kk[En], vv[En];
#pragma unroll
    for (int e = 0; e < En; ++e) { kk[e] = 0.f; vv[e] = 0.f; }
    for (int ch = 0; ch < 4; ++ch) {
        const int c0 = cg * 64 + ch * 16;
        float f[16];
#pragma unroll
        for (int jj = 0; jj < 16; ++jj) f[jj] = feat[(size_t)(kb * 256 + c0 + jj) * NS + s];
#pragma unroll
        for (int jj = 0; jj < 16; ++jj) {
            const int c = c0 + jj;
#pragma unroll
            for (int e = 0; e < En; ++e) {
                kk[e] += w_k[e * 256 + c] * f[jj];
                vv[e] += w_v[e * 256 + c] * f[jj];
            }
        }
    }
#pragma unroll
    for (int e = 0; e < En; ++e) {
        pkv[((size_t)(g * NS + s)) * 24 + e] = kk[e];
        pkv[((size_t)(g * NS + s)) * 24 + 12 + e] = vv[e];
    }
}

// ---------- K1: pool + qraw(bf16) + GN-in stats (last block finalizes st1) ----------
__global__ __launch_bounds__(256) void k1_pool(const float* __restrict__ cost,
                                               const float* __restrict__ w_q,
                                               const float* __restrict__ gniw,
                                               unsigned short* __restrict__ qr,
                                               float2* __restrict__ part1,
                                               float2* __restrict__ st1,
                                               unsigned* __restrict__ cnt) {
    __shared__ float wqg[En * Cn];
    __shared__ unsigned lastf;
    const int b = blockIdx.y, tid = threadIdx.x;
    for (int i = tid; i < En * Cn; i += 256) wqg[i] = w_q[i] * gniw[i & 31];
    __syncthreads();
    const int n = blockIdx.x * 256 + tid;
    const int d = n >> 11, r = n & 2047, hq = r >> 6, wq = r & 63;
    const float* base = cost + (size_t)b * PERB + (size_t)d * 8192 + (hq * 2) * Wn + wq * 2;
    float s = 0.f, ss = 0.f;
    float q[En];
#pragma unroll
    for (int e = 0; e < En; ++e) q[e] = 0.f;
#pragma unroll 4
    for (int c = 0; c < Cn; ++c) {
        const float* src = base + (size_t)c * DHW;
        float2 t0 = *reinterpret_cast<const float2*>(src);
        float2 t1 = *reinterpret_cast<const float2*>(src + Wn);
        float ps = t0.x + t0.y + t1.x + t1.y;
        s += ps;
        ss += t0.x * t0.x + t0.y * t0.y + t1.x * t1.x + t1.y * t1.y;
        float pv = 0.25f * ps;
#pragma unroll
        for (int e = 0; e < En; ++e) q[e] += wqg[e * Cn + c] * pv;
    }
#pragma unroll
    for (int e = 0; e < En; ++e) qr[(size_t)(b * En + e) * NPB + n] = bf16b(q[e]);
    float2 rp = block_red2(s, ss);
    if (!tid) part1[b * NBLK + blockIdx.x] = rp;

    __threadfence();
    if (!tid) { unsigned old = atomicAdd(cnt, 1u); lastf = (old == 4u * NBLK - 1u); }
    __syncthreads();
    if (lastf) {
        __threadfence();
        for (int bb = 0; bb < 4; ++bb) {
            float s2 = 0.f, ss2 = 0.f;
            for (int i = tid; i < NBLK; i += 256) {
                float2 v = part1[bb * NBLK + i];
                s2 += v.x; ss2 += v.y;
            }
            float2 t = block_red2(s2, ss2);
            if (!tid) {
                float m = t.x / (float)PERB;
                float var = t.y / (float)PERB - m * m;
                st1[bb] = make_float2(m, rsqrtf(var + EPS));
            }
        }
    }
}

// ---------- K2: attention + out-proj -> zb; fused y-stats (last block -> st2) ----------
__global__ __launch_bounds__(256) void k_attn_ystats(
    const float* __restrict__ cost, const unsigned short* __restrict__ qr,
    const float* __restrict__ pkv, const float* __restrict__ w_q,
    const float* __restrict__ gniw, const float* __restrict__ gnib,
    const float2* __restrict__ st1, const float* __restrict__ w_out,
    const float* __restrict__ gamma_p,
    unsigned short* __restrict__ zb, float2* __restrict__ part2,
    float2* __restrict__ st2, unsigned* __restrict__ cnt) {
    __shared__ float Ks[NS * En], Vs[NS * En], WOs[Cn * En], QBs[En];
    __shared__ float plB[128 * 13];
    __shared__ unsigned short zsl[Cn * 6 * 64];  // [c][row: 0..3 own, 4 haloTop, 5 haloBot][w]
    __shared__ float kred[2];
    __shared__ float kscs_sh;
    __shared__ unsigned lastf;

    const int x = blockIdx.x, b = blockIdx.y, tid = threadIdx.x;
    const int d = x >> 3, j = x & 7;

    // prologue: combine K/V partials, weights, q-bias
    for (int i = tid; i < NS * En; i += 256) {
        int s = i / En, e = i - s * En;
        size_t base = ((size_t)((b * 4) * NS + s)) * 24 + e;
        Ks[i] = pkv[base] + pkv[base + 3072] + pkv[base + 6144] + pkv[base + 9216];
        Vs[i] = pkv[base + 12] + pkv[base + 3084] + pkv[base + 6156] + pkv[base + 9228];
    }
    for (int i = tid; i < Cn * En; i += 256) WOs[i] = w_out[i];
    const float2 s1 = st1[b];
    if (tid < En) {
        float acc = 0.f;
        for (int c = 0; c < Cn; ++c)
            acc += w_q[tid * Cn + c] * (gnib[c] - s1.x * s1.y * gniw[c]);
        QBs[tid] = SQK * acc;
    }
    __syncthreads();
    if (tid < NS) {
        float n2 = 0.f;
#pragma unroll
        for (int e = 0; e < En; ++e) { float k = Ks[tid * En + e]; n2 += k * k; }
#pragma unroll
        for (int off = 32; off; off >>= 1) n2 = fmaxf(n2, __shfl_down(n2, off, 64));
        if (!(tid & 63)) kred[tid >> 6] = n2;
    }
    __syncthreads();
    if (!tid) kscs_sh = sqrtf(fmaxf(kred[0], kred[1]));
    __syncthreads();
    const float kscs = kscs_sh;
    const float qsc = s1.y * SQK;

    // ----- own 256 positions -----
    {
        const int n = x * 256 + tid;
        float q[En], qn2 = 0.f;
#pragma unroll
        for (int e = 0; e < En; ++e) {
            q[e] = qsc * b2f(qr[(size_t)(b * En + e) * NPB + n]) + QBs[e];
            qn2 += q[e] * q[e];
        }
        const float ub = sqrtf(qn2) * kscs;
        float l = 0.f, o[En];
#pragma unroll
        for (int e = 0; e < En; ++e) o[e] = 0.f;
        for (int s = 0; s < NS; ++s) {
            float dot = 0.f;
#pragma unroll
            for (int e = 0; e < En; ++e) dot += q[e] * Ks[s * En + e];
            float pe = __expf(dot - ub);
            l += pe;
#pragma unroll
            for (int e = 0; e < En; ++e) o[e] += pe * Vs[s * En + e];
        }
        const float inv = 1.0f / l;
        const int lrow = tid >> 6, lw = tid & 63;
        for (int c = 0; c < Cn; ++c) {
            float z = 0.f;
#pragma unroll
            for (int e = 0; e < En; ++e) z += WOs[c * En + e] * o[e];
            unsigned short zv = bf16b(z * inv);
            zb[(size_t)(b * Cn + c) * NPB + n] = zv;
            zsl[c * 384 + lrow * 64 + lw] = zv;
        }
    }

    // ----- halo rows (recompute; key-loop split over thread pairs) -----
    {
        const int t = tid & 127, half = tid >> 7;
        const int which = t >> 6;  // 0 = top (4j-1), 1 = bottom (4j+4)
        const int lw = t & 63;
        const int prow = which ? (4 * j + 4) : (4 * j - 1);
        const bool valid = which ? (j < 7) : (j > 0);
        float l = 0.f, o[En];
#pragma unroll
        for (int e = 0; e < En; ++e) o[e] = 0.f;
        if (valid) {
            const int n = d * 2048 + prow * 64 + lw;
            float q[En], qn2 = 0.f;
#pragma unroll
            for (int e = 0; e < En; ++e) {
                q[e] = qsc * b2f(qr[(size_t)(b * En + e) * NPB + n]) + QBs[e];
                qn2 += q[e] * q[e];
            }
            const float ub = sqrtf(qn2) * kscs;
            for (int s = half * 64; s < half * 64 + 64; ++s) {
                float dot = 0.f;
#pragma unroll
                for (int e = 0; e < En; ++e) dot += q[e] * Ks[s * En + e];
                float pe = __expf(dot - ub);
                l += pe;
#pragma unroll
                for (int e = 0; e < En; ++e) o[e] += pe * Vs[s * En + e];
            }
        }
        if (half) {
            plB[t * 13] = l;
#pragma unroll
            for (int e = 0; e < En; ++e) plB[t * 13 + 1 + e] = o[e];
        }
        __syncthreads();
        if (!half && valid) {
            l += plB[t * 13];
#pragma unroll
            for (int e = 0; e < En; ++e) o[e] += plB[t * 13 + 1 + e];
            const float inv = 1.0f / l;
            const int zr = which ? 5 : 4;
            for (int c = 0; c < Cn; ++c) {
                float z = 0.f;
#pragma unroll
                for (int e = 0; e < En; ++e) z += WOs[c * En + e] * o[e];
                zsl[c * 384 + zr * 64 + lw] = bf16b(z * inv);
            }
        }
    }
    __syncthreads();

    // ----- fused y-stats over full-res rows [8j, 8j+8) of all 32 channels -----
    float ys = 0.f, yss = 0.f;
    {
        const float g = gamma_p[0];
        const int h = tid >> 5, wqd = tid & 31;
        const int gh = 8 * j + h;
        int h0 = (gh - 1) >> 1;
        const float wh0 = (gh & 1) ? 0.75f : 0.25f;
        int h1 = h0 + 1;
        h0 = h0 < 0 ? 0 : h0; h1 = h1 > HQ - 1 ? HQ - 1 : h1;
        int lr0 = h0 - 4 * j, lr1 = h1 - 4 * j;
        lr0 = (lr0 < 0) ? 4 : lr0;
        lr1 = (lr1 > 3) ? 5 : lr1;
        const float* cbase = cost + (size_t)b * PERB + (size_t)d * 8192 + (size_t)gh * Wn + wqd * 4;
        for (int c = 0; c < Cn; ++c) {
            f4v cv = *reinterpret_cast<const f4v*>(cbase + (size_t)c * DHW);
            const unsigned short* z0 = zsl + c * 384 + lr0 * 64;
            const unsigned short* z1 = zsl + c * 384 + lr1 * 64;
#pragma unroll
            for (int p = 0; p < 4; ++p) {
                int w = wqd * 4 + p;
                int w0 = (w - 1) >> 1;
                float ww0 = (w & 1) ? 0.75f : 0.25f;
                int w1 = w0 + 1;
                w0 = w0 < 0 ? 0 : w0; w1 = w1 > WQ - 1 ? WQ - 1 : w1;
                float u = wh0 * (ww0 * b2f(z0[w0]) + (1.f - ww0) * b2f(z0[w1])) +
                          (1.f - wh0) * (ww0 * b2f(z1[w0]) + (1.f - ww0) * b2f(z1[w1]));
                float y = cv[p] + g * bf16_rne(u);
                ys += y; yss += y * y;
            }
        }
    }
    float2 rp = block_red2(ys, yss);
    if (!tid) part2[b * NBLK + x] = rp;

    __threadfence();
    if (!tid) { unsigned old = atomicAdd(cnt + 1, 1u); lastf = (old == 4u * NBLK - 1u); }
    __syncthreads();
    if (lastf) {
        __threadfence();
        for (int bb = 0; bb < 4; ++bb) {
            float s2 = 0.f, ss2 = 0.f;
            for (int i = tid; i < NBLK; i += 256) {
                float2 v = part2[bb * NBLK + i];
                s2 += v.x; ss2 += v.y;
            }
            float2 t = block_red2(s2, ss2);
            if (!tid) {
                float m = t.x / (float)PERB;
                float var = t.y / (float)PERB - m * m;
                st2[bb] = make_float2(m, rsqrtf(var + EPS));
            }
        }
    }
}

// ---------- K3: recompute y, final GroupNorm, nontemporal store ----------
__global__ __launch_bounds__(256) void k_final(const float* __restrict__ cost,
                                               const unsigned short* __restrict__ zb,
                                               const float* __restrict__ gamma_p,
                                               const float2* __restrict__ st2,
                                               const float* __restrict__ gow,
                                               const float* __restrict__ gob,
                                               float* __restrict__ out) {
    const int blk = blockIdx.x;
    __shared__ unsigned short zs[HQ * WQ];
    const int tid = threadIdx.x;
    {
        const unsigned int* zsrc = (const unsigned int*)(zb + (size_t)blk * 2048);
        for (int i = tid; i < 1024; i += 256) ((unsigned int*)zs)[i] = zsrc[i];
    }
    __syncthreads();
    const int b = blk / (Cn * Dn);
    const int c = (blk / Dn) % Cn;
    const float g = gamma_p[0];
    float2 st = st2[b];
    const float m = st.x, sc = st.y * gow[c], bi = gob[c];
    const f4v* cq = (const f4v*)(cost + (size_t)blk * 8192);
    f4v* oq = (f4v*)(out + (size_t)blk * 8192);
#pragma unroll
    for (int k = 0; k < 8; ++k) {
        int qd = tid + 256 * k;
        int h = qd >> 5, w4 = (qd & 31) << 2;
        f4v cv = cq[qd];
        int h0 = (h - 1) >> 1;
        float wh0 = (h & 1) ? 0.75f : 0.25f;
        int h1 = h0 + 1;
        h0 = h0 < 0 ? 0 : h0; h1 = h1 > HQ - 1 ? HQ - 1 : h1;
        const unsigned short* r0 = zs + h0 * WQ;
        const unsigned short* r1 = zs + h1 * WQ;
        f4v ov;
#pragma unroll
        for (int p = 0; p < 4; ++p) {
            int w = w4 + p;
            int w0 = (w - 1) >> 1;
            float ww0 = (w & 1) ? 0.75f : 0.25f;
            int w1 = w0 + 1;
            w0 = w0 < 0 ? 0 : w0; w1 = w1 > WQ - 1 ? WQ - 1 : w1;
            float u = wh0 * (ww0 * b2f(r0[w0]) + (1.f - ww0) * b2f(r0[w1])) +
                      (1.f - wh0) * (ww0 * b2f(r1[w0]) + (1.f - ww0) * b2f(r1[w1]));
            float y = cv[p] + g * bf16_rne(u);
            ov[p] = (y - m) * sc + bi;
        }
        __builtin_nontemporal_store(ov, oq + qd);
    }
}

extern "C" void kernel_launch(void* const* d_in, const int* in_sizes, int n_in,
                              void* d_out, int out_size, void* d_ws, size_t ws_size,
                              hipStream_t stream) {
    const float* cost  = (const float*)d_in[0];
    const float* feat  = (const float*)d_in[1];
    const float* w_q   = (const float*)d_in[2];
    const float* w_k   = (const float*)d_in[3];
    const float* w_v   = (const float*)d_in[4];
    const float* w_out = (const float*)d_in[5];
    const float* gniw  = (const float*)d_in[6];
    const float* gnib  = (const float*)d_in[7];
    const float* gow   = (const float*)d_in[8];
    const float* gob   = (const float*)d_in[9];
    const float* gamma = (const float*)d_in[10];

    float* ws = (float*)d_ws;
    float* outp = (float*)d_out;

    unsigned short* zb = (unsigned short*)(ws + OFF_ZB);
    unsigned short* qr = (unsigned short*)(ws + OFF_QR);
    float2* part1 = (float2*)(ws + OFF_P1);
    float2* part2 = (float2*)(ws + OFF_P2);
    float2* st1 = (float2*)(ws + OFF_ST1);
    float2* st2 = (float2*)(ws + OFF_ST2);
    float* pkv = ws + OFF_PKV;
    unsigned* cnt = (unsigned*)(ws + OFF_CNT);

    k_kv<<<16, 128, 0, stream>>>(feat, w_k, w_v, pkv, cnt);
    k1_pool<<<dim3(NBLK, Bn), 256, 0, stream>>>(cost, w_q, gniw, qr, part1, st1, cnt);
    k_attn_ystats<<<dim3(NBLK, Bn), 256, 0, stream>>>(cost, qr, pkv, w_q, gniw, gnib, st1,
                                                      w_out, gamma, zb, part2, st2, cnt);
    k_final<<<Bn * Cn * Dn, 256, 0, stream>>>(cost, zb, gamma, st2, gow, gob, outp);
}

// Round 7
// 229.327 us; speedup vs baseline: 2.5689x; 2.5689x over previous
//
#include <hip/hip_runtime.h>

typedef float f4v __attribute__((ext_vector_type(4)));

namespace {
constexpr int Bn = 4, Cn = 32, Dn = 48, Hn = 64, Wn = 128;
constexpr int HQ = 32, WQ = 64;
constexpr int NPB = Dn * HQ * WQ;   // 98304 pooled positions / batch
constexpr int DHW = Dn * Hn * Wn;   // 393216
constexpr int PERB = Cn * DHW;      // 12582912 elements / batch
constexpr int NS = 128, En = 12;
constexpr float EPS = 1e-5f;
constexpr float SQK = 0.2886751345948129f;  // 1/sqrt(12)
constexpr int NBLK = 384;                   // grid.x of big kernels

// workspace float offsets
constexpr size_t OFF_ZB  = 0;                      // bf16[4*32*98304] -> 6291456 floats
constexpr size_t OFF_QR  = 6291456;                // bf16[4*12*98304] -> 2359296 floats
constexpr size_t OFF_P1  = OFF_QR + 2359296;       // float2[4*384] -> 3072 floats
constexpr size_t OFF_P2  = OFF_P1 + 3072;          // float2[4*384] -> 3072 floats
constexpr size_t OFF_ST1 = OFF_P2 + 3072;          // float2[4]
constexpr size_t OFF_ST2 = OFF_ST1 + 8;            // float2[4]
constexpr size_t OFF_PKV = OFF_ST2 + 8;            // 16*128*24 = 49152
}  // namespace

__device__ inline unsigned short bf16b(float x) {
    unsigned u = __float_as_uint(x);
    return (unsigned short)((u + 0x7fffu + ((u >> 16) & 1u)) >> 16);
}
__device__ inline float b2f(unsigned short h) { return __uint_as_float(((unsigned)h) << 16); }
__device__ inline float bf16_rne(float x) {
    unsigned u = __float_as_uint(x);
    u = (u + 0x7fffu + ((u >> 16) & 1u)) & 0xffff0000u;
    return __uint_as_float(u);
}

// block = 256 threads; reentrant-safe (leading barrier).
__device__ inline float2 block_red2(float s, float ss) {
#pragma unroll
    for (int off = 32; off; off >>= 1) {
        s += __shfl_down(s, off, 64);
        ss += __shfl_down(ss, off, 64);
    }
    __shared__ float red[8];
    int lane = threadIdx.x & 63, w = threadIdx.x >> 6;
    __syncthreads();
    if (!lane) { red[w] = s; red[4 + w] = ss; }
    __syncthreads();
    return make_float2(red[0] + red[1] + red[2] + red[3],
                       red[4] + red[5] + red[6] + red[7]);
}

// ---------- K1: pool + qraw(bf16) + GN-in partial stats + (16 blocks) K/V partials ----------
__global__ __launch_bounds__(256) void k1_pool(const float* __restrict__ cost,
                                               const float* __restrict__ feat,
                                               const float* __restrict__ w_q,
                                               const float* __restrict__ w_k,
                                               const float* __restrict__ w_v,
                                               const float* __restrict__ gniw,
                                               unsigned short* __restrict__ qr,
                                               float2* __restrict__ part1,
                                               float* __restrict__ pkv) {
    __shared__ float wqg[En * Cn];
    const int b = blockIdx.y, tid = threadIdx.x;
    for (int i = tid; i < En * Cn; i += 256) wqg[i] = w_q[i] * gniw[i & 31];
    __syncthreads();
    const int n = blockIdx.x * 256 + tid;
    const int d = n >> 11, r = n & 2047, hq = r >> 6, wq = r & 63;
    const float* base = cost + (size_t)b * PERB + (size_t)d * 8192 + (hq * 2) * Wn + wq * 2;
    float s = 0.f, ss = 0.f;
    float q[En];
#pragma unroll
    for (int e = 0; e < En; ++e) q[e] = 0.f;
#pragma unroll 4
    for (int c = 0; c < Cn; ++c) {
        const float* src = base + (size_t)c * DHW;
        float2 t0 = *reinterpret_cast<const float2*>(src);
        float2 t1 = *reinterpret_cast<const float2*>(src + Wn);
        float ps = t0.x + t0.y + t1.x + t1.y;
        s += ps;
        ss += t0.x * t0.x + t0.y * t0.y + t1.x * t1.x + t1.y * t1.y;
        float pv = 0.25f * ps;
#pragma unroll
        for (int e = 0; e < En; ++e) q[e] += wqg[e * Cn + c] * pv;
    }
#pragma unroll
    for (int e = 0; e < En; ++e) qr[(size_t)(b * En + e) * NPB + n] = bf16b(q[e]);
    float2 rp = block_red2(s, ss);
    if (!tid) part1[b * NBLK + blockIdx.x] = rp;

    // K/V partials: 16 blocks (b==0, x<16). group g = x: kb = g>>2 (batch), cg = g&3 (64-ch group)
    if (b == 0 && blockIdx.x < 16 && tid < NS) {
        const int g = blockIdx.x, kb = g >> 2, cg = g & 3, sI = tid;
        float kk[En], vv[En];
#pragma unroll
        for (int e = 0; e < En; ++e) { kk[e] = 0.f; vv[e] = 0.f; }
        for (int ch = 0; ch < 4; ++ch) {
            const int c0 = cg * 64 + ch * 16;
            float f[16];
#pragma unroll
            for (int jj = 0; jj < 16; ++jj) f[jj] = feat[(size_t)(kb * 256 + c0 + jj) * NS + sI];
#pragma unroll
            for (int jj = 0; jj < 16; ++jj) {
                const int c = c0 + jj;
#pragma unroll
                for (int e = 0; e < En; ++e) {
                    kk[e] += w_k[e * 256 + c] * f[jj];
                    vv[e] += w_v[e * 256 + c] * f[jj];
                }
            }
        }
#pragma unroll
        for (int e = 0; e < En; ++e) {
            pkv[((size_t)(g * NS + sI)) * 24 + e] = kk[e];
            pkv[((size_t)(g * NS + sI)) * 24 + 12 + e] = vv[e];
        }
    }
}

// ---------- K2: finalize stats1 (4 blocks) ----------
__global__ __launch_bounds__(256) void k_st1(const float2* __restrict__ part1,
                                             float2* __restrict__ st1) {
    const int b = blockIdx.x, tid = threadIdx.x;
    float s = 0.f, ss = 0.f;
    for (int i = tid; i < NBLK; i += 256) {
        float2 v = part1[b * NBLK + i];
        s += v.x; ss += v.y;
    }
    float2 t = block_red2(s, ss);
    if (!tid) {
        float m = t.x / (float)PERB;
        float var = t.y / (float)PERB - m * m;
        st1[b] = make_float2(m, rsqrtf(var + EPS));
    }
}

// ---------- K3: attention + out-proj -> zb; fused y-stats (halo recompute) ----------
__global__ __launch_bounds__(256) void k_attn_ystats(
    const float* __restrict__ cost, const unsigned short* __restrict__ qr,
    const float* __restrict__ pkv, const float* __restrict__ w_q,
    const float* __restrict__ gniw, const float* __restrict__ gnib,
    const float2* __restrict__ st1, const float* __restrict__ w_out,
    const float* __restrict__ gamma_p,
    unsigned short* __restrict__ zb, float2* __restrict__ part2) {
    __shared__ float Ks[NS * En], Vs[NS * En], WOs[Cn * En], QBs[En];
    __shared__ float plB[128 * 13];
    __shared__ unsigned short zsl[Cn * 6 * 64];  // [c][row: 0..3 own, 4 haloTop, 5 haloBot][w]
    __shared__ float kred[2];
    __shared__ float kscs_sh;

    const int x = blockIdx.x, b = blockIdx.y, tid = threadIdx.x;
    const int d = x >> 3, j = x & 7;

    // prologue: combine K/V partials, weights, q-bias
    for (int i = tid; i < NS * En; i += 256) {
        int s = i / En, e = i - s * En;
        size_t base = ((size_t)((b * 4) * NS + s)) * 24 + e;
        Ks[i] = pkv[base] + pkv[base + 3072] + pkv[base + 6144] + pkv[base + 9216];
        Vs[i] = pkv[base + 12] + pkv[base + 3084] + pkv[base + 6156] + pkv[base + 9228];
    }
    for (int i = tid; i < Cn * En; i += 256) WOs[i] = w_out[i];
    const float2 s1 = st1[b];
    if (tid < En) {
        float acc = 0.f;
        for (int c = 0; c < Cn; ++c)
            acc += w_q[tid * Cn + c] * (gnib[c] - s1.x * s1.y * gniw[c]);
        QBs[tid] = SQK * acc;
    }
    __syncthreads();
    if (tid < NS) {
        float n2 = 0.f;
#pragma unroll
        for (int e = 0; e < En; ++e) { float k = Ks[tid * En + e]; n2 += k * k; }
#pragma unroll
        for (int off = 32; off; off >>= 1) n2 = fmaxf(n2, __shfl_down(n2, off, 64));
        if (!(tid & 63)) kred[tid >> 6] = n2;
    }
    __syncthreads();
    if (!tid) kscs_sh = sqrtf(fmaxf(kred[0], kred[1]));
    __syncthreads();
    const float kscs = kscs_sh;
    const float qsc = s1.y * SQK;

    // ----- own 256 positions -----
    {
        const int n = x * 256 + tid;
        float q[En], qn2 = 0.f;
#pragma unroll
        for (int e = 0; e < En; ++e) {
            q[e] = qsc * b2f(qr[(size_t)(b * En + e) * NPB + n]) + QBs[e];
            qn2 += q[e] * q[e];
        }
        const float ub = sqrtf(qn2) * kscs;  // Cauchy-Schwarz >= max logit
        float l = 0.f, o[En];
#pragma unroll
        for (int e = 0; e < En; ++e) o[e] = 0.f;
        for (int s = 0; s < NS; ++s) {
            float dot = 0.f;
#pragma unroll
            for (int e = 0; e < En; ++e) dot += q[e] * Ks[s * En + e];
            float pe = __expf(dot - ub);
            l += pe;
#pragma unroll
            for (int e = 0; e < En; ++e) o[e] += pe * Vs[s * En + e];
        }
        const float inv = 1.0f / l;
        const int lrow = tid >> 6, lw = tid & 63;
        for (int c = 0; c < Cn; ++c) {
            float z = 0.f;
#pragma unroll
            for (int e = 0; e < En; ++e) z += WOs[c * En + e] * o[e];
            unsigned short zv = bf16b(z * inv);
            zb[(size_t)(b * Cn + c) * NPB + n] = zv;
            zsl[c * 384 + lrow * 64 + lw] = zv;
        }
    }

    // ----- halo rows (recompute; key-loop split over thread pairs) -----
    {
        const int t = tid & 127, half = tid >> 7;
        const int which = t >> 6;  // 0 = top (4j-1), 1 = bottom (4j+4)
        const int lw = t & 63;
        const int prow = which ? (4 * j + 4) : (4 * j - 1);
        const bool valid = which ? (j < 7) : (j > 0);
        float l = 0.f, o[En];
#pragma unroll
        for (int e = 0; e < En; ++e) o[e] = 0.f;
        if (valid) {
            const int n = d * 2048 + prow * 64 + lw;
            float q[En], qn2 = 0.f;
#pragma unroll
            for (int e = 0; e < En; ++e) {
                q[e] = qsc * b2f(qr[(size_t)(b * En + e) * NPB + n]) + QBs[e];
                qn2 += q[e] * q[e];
            }
            const float ub = sqrtf(qn2) * kscs;
            for (int s = half * 64; s < half * 64 + 64; ++s) {
                float dot = 0.f;
#pragma unroll
                for (int e = 0; e < En; ++e) dot += q[e] * Ks[s * En + e];
                float pe = __expf(dot - ub);
                l += pe;
#pragma unroll
                for (int e = 0; e < En; ++e) o[e] += pe * Vs[s * En + e];
            }
        }
        if (half) {
            plB[t * 13] = l;
#pragma unroll
            for (int e = 0; e < En; ++e) plB[t * 13 + 1 + e] = o[e];
        }
        __syncthreads();
        if (!half && valid) {
            l += plB[t * 13];
#pragma unroll
            for (int e = 0; e < En; ++e) o[e] += plB[t * 13 + 1 + e];
            const float inv = 1.0f / l;
            const int zr = which ? 5 : 4;
            for (int c = 0; c < Cn; ++c) {
                float z = 0.f;
#pragma unroll
                for (int e = 0; e < En; ++e) z += WOs[c * En + e] * o[e];
                zsl[c * 384 + zr * 64 + lw] = bf16b(z * inv);
            }
        }
    }
    __syncthreads();

    // ----- fused y-stats over full-res rows [8j, 8j+8) of all 32 channels -----
    float ys = 0.f, yss = 0.f;
    {
        const float g = gamma_p[0];
        const int h = tid >> 5, wqd = tid & 31;
        const int gh = 8 * j + h;
        int h0 = (gh - 1) >> 1;
        const float wh0 = (gh & 1) ? 0.75f : 0.25f;
        int h1 = h0 + 1;
        h0 = h0 < 0 ? 0 : h0; h1 = h1 > HQ - 1 ? HQ - 1 : h1;
        int lr0 = h0 - 4 * j, lr1 = h1 - 4 * j;
        lr0 = (lr0 < 0) ? 4 : lr0;
        lr1 = (lr1 > 3) ? 5 : lr1;
        const float* cbase = cost + (size_t)b * PERB + (size_t)d * 8192 + (size_t)gh * Wn + wqd * 4;
        for (int c = 0; c < Cn; ++c) {
            f4v cv = *reinterpret_cast<const f4v*>(cbase + (size_t)c * DHW);
            const unsigned short* z0 = zsl + c * 384 + lr0 * 64;
            const unsigned short* z1 = zsl + c * 384 + lr1 * 64;
#pragma unroll
            for (int p = 0; p < 4; ++p) {
                int w = wqd * 4 + p;
                int w0 = (w - 1) >> 1;
                float ww0 = (w & 1) ? 0.75f : 0.25f;
                int w1 = w0 + 1;
                w0 = w0 < 0 ? 0 : w0; w1 = w1 > WQ - 1 ? WQ - 1 : w1;
                float u = wh0 * (ww0 * b2f(z0[w0]) + (1.f - ww0) * b2f(z0[w1])) +
                          (1.f - wh0) * (ww0 * b2f(z1[w0]) + (1.f - ww0) * b2f(z1[w1]));
                float y = cv[p] + g * bf16_rne(u);
                ys += y; yss += y * y;
            }
        }
    }
    float2 rp = block_red2(ys, yss);
    if (!tid) part2[b * NBLK + x] = rp;
}

// ---------- K4: finalize stats2 (4 blocks) ----------
__global__ __launch_bounds__(256) void k_fin2(const float2* __restrict__ part2,
                                              float2* __restrict__ st2) {
    const int b = blockIdx.x, tid = threadIdx.x;
    float s = 0.f, ss = 0.f;
    for (int i = tid; i < NBLK; i += 256) {
        float2 v = part2[b * NBLK + i];
        s += v.x; ss += v.y;
    }
    float2 t = block_red2(s, ss);
    if (!tid) {
        float m = t.x / (float)PERB;
        float var = t.y / (float)PERB - m * m;
        st2[b] = make_float2(m, rsqrtf(var + EPS));
    }
}

// ---------- K5: recompute y, final GroupNorm, nontemporal store ----------
__global__ __launch_bounds__(256) void k_final(const float* __restrict__ cost,
                                               const unsigned short* __restrict__ zb,
                                               const float* __restrict__ gamma_p,
                                               const float2* __restrict__ st2,
                                               const float* __restrict__ gow,
                                               const float* __restrict__ gob,
                                               float* __restrict__ out) {
    const int blk = blockIdx.x;
    __shared__ unsigned short zs[HQ * WQ];
    const int tid = threadIdx.x;
    {
        const unsigned int* zsrc = (const unsigned int*)(zb + (size_t)blk * 2048);
        for (int i = tid; i < 1024; i += 256) ((unsigned int*)zs)[i] = zsrc[i];
    }
    __syncthreads();
    const int b = blk / (Cn * Dn);
    const int c = (blk / Dn) % Cn;
    const float g = gamma_p[0];
    float2 st = st2[b];
    const float m = st.x, sc = st.y * gow[c], bi = gob[c];
    const f4v* cq = (const f4v*)(cost + (size_t)blk * 8192);
    f4v* oq = (f4v*)(out + (size_t)blk * 8192);
#pragma unroll
    for (int k = 0; k < 8; ++k) {
        int qd = tid + 256 * k;
        int h = qd >> 5, w4 = (qd & 31) << 2;
        f4v cv = cq[qd];
        int h0 = (h - 1) >> 1;
        float wh0 = (h & 1) ? 0.75f : 0.25f;
        int h1 = h0 + 1;
        h0 = h0 < 0 ? 0 : h0; h1 = h1 > HQ - 1 ? HQ - 1 : h1;
        const unsigned short* r0 = zs + h0 * WQ;
        const unsigned short* r1 = zs + h1 * WQ;
        f4v ov;
#pragma unroll
        for (int p = 0; p < 4; ++p) {
            int w = w4 + p;
            int w0 = (w - 1) >> 1;
            float ww0 = (w & 1) ? 0.75f : 0.25f;
            int w1 = w0 + 1;
            w0 = w0 < 0 ? 0 : w0; w1 = w1 > WQ - 1 ? WQ - 1 : w1;
            float u = wh0 * (ww0 * b2f(r0[w0]) + (1.f - ww0) * b2f(r0[w1])) +
                      (1.f - wh0) * (ww0 * b2f(r1[w0]) + (1.f - ww0) * b2f(r1[w1]));
            float y = cv[p] + g * bf16_rne(u);
            ov[p] = (y - m) * sc + bi;
        }
        __builtin_nontemporal_store(ov, oq + qd);
    }
}

extern "C" void kernel_launch(void* const* d_in, const int* in_sizes, int n_in,
                              void* d_out, int out_size, void* d_ws, size_t ws_size,
                              hipStream_t stream) {
    const float* cost  = (const float*)d_in[0];
    const float* feat  = (const float*)d_in[1];
    const float* w_q   = (const float*)d_in[2];
    const float* w_k   = (const float*)d_in[3];
    const float* w_v   = (const float*)d_in[4];
    const float* w_out = (const float*)d_in[5];
    const float* gniw  = (const float*)d_in[6];
    const float* gnib  = (const float*)d_in[7];
    const float* gow   = (const float*)d_in[8];
    const float* gob   = (const float*)d_in[9];
    const float* gamma = (const float*)d_in[10];

    float* ws = (float*)d_ws;
    float* outp = (float*)d_out;

    unsigned short* zb = (unsigned short*)(ws + OFF_ZB);
    unsigned short* qr = (unsigned short*)(ws + OFF_QR);
    float2* part1 = (float2*)(ws + OFF_P1);
    float2* part2 = (float2*)(ws + OFF_P2);
    float2* st1 = (float2*)(ws + OFF_ST1);
    float2* st2 = (float2*)(ws + OFF_ST2);
    float* pkv = ws + OFF_PKV;

    k1_pool<<<dim3(NBLK, Bn), 256, 0, stream>>>(cost, feat, w_q, w_k, w_v, gniw, qr, part1, pkv);
    k_st1<<<Bn, 256, 0, stream>>>(part1, st1);
    k_attn_ystats<<<dim3(NBLK, Bn), 256, 0, stream>>>(cost, qr, pkv, w_q, gniw, gnib, st1,
                                                      w_out, gamma, zb, part2);
    k_fin2<<<Bn, 256, 0, stream>>>(part2, st2);
    k_final<<<Bn * Cn * Dn, 256, 0, stream>>>(cost, zb, gamma, st2, gow, gob, outp);
}

// Round 8
// 202.234 us; speedup vs baseline: 2.9130x; 1.1340x over previous
//
#include <hip/hip_runtime.h>

typedef float f4v __attribute__((ext_vector_type(4)));

namespace {
constexpr int Bn = 4, Cn = 32, Dn = 48, Hn = 64, Wn = 128;
constexpr int HQ = 32, WQ = 64;
constexpr int NPB = Dn * HQ * WQ;   // 98304 pooled positions / batch
constexpr int DHW = Dn * Hn * Wn;   // 393216
constexpr int PERB = Cn * DHW;      // 12582912 elements / batch
constexpr int NS = 128, En = 12;
constexpr float EPS = 1e-5f;
constexpr float SQK = 0.2886751345948129f;  // 1/sqrt(12)
constexpr int NBLK = 384;                   // grid.x of k1

// workspace float offsets
constexpr size_t OFF_ZB  = 0;                      // bf16[4*32*98304] -> 6291456 floats
constexpr size_t OFF_QR  = 6291456;                // bf16[4*12*98304] -> 2359296 floats
constexpr size_t OFF_P1  = OFF_QR + 2359296;       // float2[4*384] -> 3072 floats
constexpr size_t OFF_P2  = OFF_P1 + 3072;          // float2[6144] -> 12288 floats
constexpr size_t OFF_ST1 = OFF_P2 + 12288;         // float2[4]
constexpr size_t OFF_ST2 = OFF_ST1 + 8;            // float2[4]
constexpr size_t OFF_PKV = OFF_ST2 + 8;            // 16*128*24 = 49152
}  // namespace

__device__ inline unsigned short bf16b(float x) {
    unsigned u = __float_as_uint(x);
    return (unsigned short)((u + 0x7fffu + ((u >> 16) & 1u)) >> 16);
}
__device__ inline float b2f(unsigned short h) { return __uint_as_float(((unsigned)h) << 16); }
__device__ inline float bf16_rne(float x) {
    unsigned u = __float_as_uint(x);
    u = (u + 0x7fffu + ((u >> 16) & 1u)) & 0xffff0000u;
    return __uint_as_float(u);
}

// block = 256 threads; reentrant-safe (leading barrier).
__device__ inline float2 block_red2(float s, float ss) {
#pragma unroll
    for (int off = 32; off; off >>= 1) {
        s += __shfl_down(s, off, 64);
        ss += __shfl_down(ss, off, 64);
    }
    __shared__ float red[8];
    int lane = threadIdx.x & 63, w = threadIdx.x >> 6;
    __syncthreads();
    if (!lane) { red[w] = s; red[4 + w] = ss; }
    __syncthreads();
    return make_float2(red[0] + red[1] + red[2] + red[3],
                       red[4] + red[5] + red[6] + red[7]);
}

// ---------- K1: pool + qraw(bf16) + GN-in partial stats + (16 blocks) K/V partials ----------
__global__ __launch_bounds__(256) void k1_pool(const float* __restrict__ cost,
                                               const float* __restrict__ feat,
                                               const float* __restrict__ w_q,
                                               const float* __restrict__ w_k,
                                               const float* __restrict__ w_v,
                                               const float* __restrict__ gniw,
                                               unsigned short* __restrict__ qr,
                                               float2* __restrict__ part1,
                                               float* __restrict__ pkv) {
    __shared__ float wqg[En * Cn];
    const int b = blockIdx.y, tid = threadIdx.x;
    for (int i = tid; i < En * Cn; i += 256) wqg[i] = w_q[i] * gniw[i & 31];
    __syncthreads();
    const int n = blockIdx.x * 256 + tid;
    const int d = n >> 11, r = n & 2047, hq = r >> 6, wq = r & 63;
    const float* base = cost + (size_t)b * PERB + (size_t)d * 8192 + (hq * 2) * Wn + wq * 2;
    float s = 0.f, ss = 0.f;
    float q[En];
#pragma unroll
    for (int e = 0; e < En; ++e) q[e] = 0.f;
#pragma unroll 4
    for (int c = 0; c < Cn; ++c) {
        const float* src = base + (size_t)c * DHW;
        float2 t0 = *reinterpret_cast<const float2*>(src);
        float2 t1 = *reinterpret_cast<const float2*>(src + Wn);
        float ps = t0.x + t0.y + t1.x + t1.y;
        s += ps;
        ss += t0.x * t0.x + t0.y * t0.y + t1.x * t1.x + t1.y * t1.y;
        float pv = 0.25f * ps;
#pragma unroll
        for (int e = 0; e < En; ++e) q[e] += wqg[e * Cn + c] * pv;
    }
#pragma unroll
    for (int e = 0; e < En; ++e) qr[(size_t)(b * En + e) * NPB + n] = bf16b(q[e]);
    float2 rp = block_red2(s, ss);
    if (!tid) part1[b * NBLK + blockIdx.x] = rp;

    // K/V partials: 16 blocks (b==0, x<16). g = x: kb = g>>2 (batch), cg = g&3 (64-ch group)
    if (b == 0 && blockIdx.x < 16 && tid < NS) {
        const int g = blockIdx.x, kb = g >> 2, cg = g & 3, sI = tid;
        float kk[En], vv[En];
#pragma unroll
        for (int e = 0; e < En; ++e) { kk[e] = 0.f; vv[e] = 0.f; }
        for (int ch = 0; ch < 4; ++ch) {
            const int c0 = cg * 64 + ch * 16;
            float f[16];
#pragma unroll
            for (int jj = 0; jj < 16; ++jj) f[jj] = feat[(size_t)(kb * 256 + c0 + jj) * NS + sI];
#pragma unroll
            for (int jj = 0; jj < 16; ++jj) {
                const int c = c0 + jj;
#pragma unroll
                for (int e = 0; e < En; ++e) {
                    kk[e] += w_k[e * 256 + c] * f[jj];
                    vv[e] += w_v[e * 256 + c] * f[jj];
                }
            }
        }
#pragma unroll
        for (int e = 0; e < En; ++e) {
            pkv[((size_t)(g * NS + sI)) * 24 + e] = kk[e];
            pkv[((size_t)(g * NS + sI)) * 24 + 12 + e] = vv[e];
        }
    }
}

// ---------- K2: finalize stats1 (4 blocks) ----------
__global__ __launch_bounds__(256) void k_st1(const float2* __restrict__ part1,
                                             float2* __restrict__ st1) {
    const int b = blockIdx.x, tid = threadIdx.x;
    float s = 0.f, ss = 0.f;
    for (int i = tid; i < NBLK; i += 256) {
        float2 v = part1[b * NBLK + i];
        s += v.x; ss += v.y;
    }
    float2 t = block_red2(s, ss);
    if (!tid) {
        float m = t.x / (float)PERB;
        float var = t.y / (float)PERB - m * m;
        st1[b] = make_float2(m, rsqrtf(var + EPS));
    }
}

// ---------- K3: attention, 3 positions/thread, f4v LDS reads ----------
__global__ __launch_bounds__(256) void k_attn(const unsigned short* __restrict__ qr,
                                              const float* __restrict__ pkv,
                                              const float* __restrict__ w_q,
                                              const float* __restrict__ gniw,
                                              const float* __restrict__ gnib,
                                              const float2* __restrict__ st1,
                                              const float* __restrict__ w_out,
                                              unsigned short* __restrict__ zb) {
    __shared__ float Ks[NS * En], Vs[NS * En], WOs[Cn * En], QBs[En];
    __shared__ float kred[2], kscs_sh;
    const int x = blockIdx.x, b = blockIdx.y, tid = threadIdx.x;

    // prologue: combine K/V partials, weights, q-bias
    for (int i = tid; i < NS * En; i += 256) {
        int s = i / En, e = i - s * En;
        size_t base = ((size_t)((b * 4) * NS + s)) * 24 + e;
        Ks[i] = pkv[base] + pkv[base + 3072] + pkv[base + 6144] + pkv[base + 9216];
        Vs[i] = pkv[base + 12] + pkv[base + 3084] + pkv[base + 6156] + pkv[base + 9228];
    }
    for (int i = tid; i < Cn * En; i += 256) WOs[i] = w_out[i];
    const float2 s1 = st1[b];
    if (tid < En) {
        float acc = 0.f;
        for (int c = 0; c < Cn; ++c)
            acc += w_q[tid * Cn + c] * (gnib[c] - s1.x * s1.y * gniw[c]);
        QBs[tid] = SQK * acc;
    }
    __syncthreads();
    if (tid < NS) {
        float n2 = 0.f;
#pragma unroll
        for (int e = 0; e < En; ++e) { float k = Ks[tid * En + e]; n2 += k * k; }
#pragma unroll
        for (int off = 32; off; off >>= 1) n2 = fmaxf(n2, __shfl_down(n2, off, 64));
        if (!(tid & 63)) kred[tid >> 6] = n2;
    }
    __syncthreads();
    if (!tid) kscs_sh = sqrtf(fmaxf(kred[0], kred[1]));
    __syncthreads();
    const float kscs = kscs_sh;
    const float qsc = s1.y * SQK;

    const int nbase = x * 768 + tid;  // positions nbase, nbase+256, nbase+512

    f4v q[3][3];
    float ub[3];
#pragma unroll
    for (int p = 0; p < 3; ++p) {
        const int n = nbase + 256 * p;
        float qn2 = 0.f;
#pragma unroll
        for (int v = 0; v < 3; ++v) {
            f4v t;
#pragma unroll
            for (int u = 0; u < 4; ++u) {
                int e = v * 4 + u;
                float qe = qsc * b2f(qr[(size_t)(b * En + e) * NPB + n]) + QBs[e];
                t[u] = qe;
                qn2 += qe * qe;
            }
            q[p][v] = t;
        }
        ub[p] = sqrtf(qn2) * kscs;  // Cauchy-Schwarz >= max logit
    }

    f4v o0[3], o1[3], o2[3];
    float l[3];
#pragma unroll
    for (int p = 0; p < 3; ++p) {
        o0[p] = (f4v)(0.f); o1[p] = (f4v)(0.f); o2[p] = (f4v)(0.f);
        l[p] = 0.f;
    }
    const f4v* K4 = (const f4v*)Ks;
    const f4v* V4 = (const f4v*)Vs;
    for (int s = 0; s < NS; ++s) {
        f4v k0 = K4[s * 3], k1 = K4[s * 3 + 1], k2 = K4[s * 3 + 2];
        f4v v0 = V4[s * 3], v1 = V4[s * 3 + 1], v2 = V4[s * 3 + 2];
#pragma unroll
        for (int p = 0; p < 3; ++p) {
            f4v d4 = q[p][0] * k0 + q[p][1] * k1 + q[p][2] * k2;
            float dot = (d4.x + d4.y) + (d4.z + d4.w);
            float pe = __expf(dot - ub[p]);
            l[p] += pe;
            o0[p] += pe * v0; o1[p] += pe * v1; o2[p] += pe * v2;
        }
    }

    const f4v* WO4 = (const f4v*)WOs;
#pragma unroll
    for (int p = 0; p < 3; ++p) {
        const float inv = 1.0f / l[p];
        const int n = nbase + 256 * p;
        for (int c = 0; c < Cn; ++c) {
            f4v z4 = WO4[c * 3] * o0[p] + WO4[c * 3 + 1] * o1[p] + WO4[c * 3 + 2] * o2[p];
            float z = ((z4.x + z4.y) + (z4.z + z4.w)) * inv;
            zb[(size_t)(b * Cn + c) * NPB + n] = bf16b(z);
        }
    }
}

// ---------- K4: y-stats; one block per (b,c,d) slice; Z slice (bf16) in LDS ----------
__global__ __launch_bounds__(256) void k_ystats(const float* __restrict__ cost,
                                                const unsigned short* __restrict__ zb,
                                                const float* __restrict__ gamma_p,
                                                float2* __restrict__ part2) {
    const int blk = blockIdx.x;  // ((b*32+c)*48+d)
    __shared__ unsigned short zs[HQ * WQ];
    const int tid = threadIdx.x;
    {
        const unsigned int* zsrc = (const unsigned int*)(zb + (size_t)blk * 2048);
        for (int i = tid; i < 1024; i += 256) ((unsigned int*)zs)[i] = zsrc[i];
    }
    __syncthreads();
    const float g = gamma_p[0];
    const f4v* cq = (const f4v*)(cost + (size_t)blk * 8192);
    float s = 0.f, ss = 0.f;
#pragma unroll
    for (int k = 0; k < 8; ++k) {
        int qd = tid + 256 * k;
        int h = qd >> 5, w4 = (qd & 31) << 2;
        f4v cv = cq[qd];
        int h0 = (h - 1) >> 1;
        float wh0 = (h & 1) ? 0.75f : 0.25f;
        int h1 = h0 + 1;
        h0 = h0 < 0 ? 0 : h0; h1 = h1 > HQ - 1 ? HQ - 1 : h1;
        const unsigned short* r0 = zs + h0 * WQ;
        const unsigned short* r1 = zs + h1 * WQ;
#pragma unroll
        for (int p = 0; p < 4; ++p) {
            int w = w4 + p;
            int w0 = (w - 1) >> 1;
            float ww0 = (w & 1) ? 0.75f : 0.25f;
            int w1 = w0 + 1;
            w0 = w0 < 0 ? 0 : w0; w1 = w1 > WQ - 1 ? WQ - 1 : w1;
            float u = wh0 * (ww0 * b2f(r0[w0]) + (1.f - ww0) * b2f(r0[w1])) +
                      (1.f - wh0) * (ww0 * b2f(r1[w0]) + (1.f - ww0) * b2f(r1[w1]));
            float y = cv[p] + g * bf16_rne(u);
            s += y; ss += y * y;
        }
    }
    float2 rp = block_red2(s, ss);
    if (!tid) part2[blk] = rp;
}

// ---------- K5: finalize stats2 (4 blocks) ----------
__global__ __launch_bounds__(256) void k_fin2(const float2* __restrict__ part2,
                                              float2* __restrict__ st2) {
    const int b = blockIdx.x, tid = threadIdx.x;
    float s = 0.f, ss = 0.f;
    for (int i = tid; i < Cn * Dn; i += 256) {
        float2 v = part2[b * Cn * Dn + i];
        s += v.x; ss += v.y;
    }
    float2 t = block_red2(s, ss);
    if (!tid) {
        float m = t.x / (float)PERB;
        float var = t.y / (float)PERB - m * m;
        st2[b] = make_float2(m, rsqrtf(var + EPS));
    }
}

// ---------- K6: recompute y, final GroupNorm, nontemporal store ----------
__global__ __launch_bounds__(256) void k_final(const float* __restrict__ cost,
                                               const unsigned short* __restrict__ zb,
                                               const float* __restrict__ gamma_p,
                                               const float2* __restrict__ st2,
                                               const float* __restrict__ gow,
                                               const float* __restrict__ gob,
                                               float* __restrict__ out) {
    const int blk = blockIdx.x;
    __shared__ unsigned short zs[HQ * WQ];
    const int tid = threadIdx.x;
    {
        const unsigned int* zsrc = (const unsigned int*)(zb + (size_t)blk * 2048);
        for (int i = tid; i < 1024; i += 256) ((unsigned int*)zs)[i] = zsrc[i];
    }
    __syncthreads();
    const int b = blk / (Cn * Dn);
    const int c = (blk / Dn) % Cn;
    const float g = gamma_p[0];
    float2 st = st2[b];
    const float m = st.x, sc = st.y * gow[c], bi = gob[c];
    const f4v* cq = (const f4v*)(cost + (size_t)blk * 8192);
    f4v* oq = (f4v*)(out + (size_t)blk * 8192);
#pragma unroll
    for (int k = 0; k < 8; ++k) {
        int qd = tid + 256 * k;
        int h = qd >> 5, w4 = (qd & 31) << 2;
        f4v cv = cq[qd];
        int h0 = (h - 1) >> 1;
        float wh0 = (h & 1) ? 0.75f : 0.25f;
        int h1 = h0 + 1;
        h0 = h0 < 0 ? 0 : h0; h1 = h1 > HQ - 1 ? HQ - 1 : h1;
        const unsigned short* r0 = zs + h0 * WQ;
        const unsigned short* r1 = zs + h1 * WQ;
        f4v ov;
#pragma unroll
        for (int p = 0; p < 4; ++p) {
            int w = w4 + p;
            int w0 = (w - 1) >> 1;
            float ww0 = (w & 1) ? 0.75f : 0.25f;
            int w1 = w0 + 1;
            w0 = w0 < 0 ? 0 : w0; w1 = w1 > WQ - 1 ? WQ - 1 : w1;
            float u = wh0 * (ww0 * b2f(r0[w0]) + (1.f - ww0) * b2f(r0[w1])) +
                      (1.f - wh0) * (ww0 * b2f(r1[w0]) + (1.f - ww0) * b2f(r1[w1]));
            float y = cv[p] + g * bf16_rne(u);
            ov[p] = (y - m) * sc + bi;
        }
        __builtin_nontemporal_store(ov, oq + qd);
    }
}

extern "C" void kernel_launch(void* const* d_in, const int* in_sizes, int n_in,
                              void* d_out, int out_size, void* d_ws, size_t ws_size,
                              hipStream_t stream) {
    const float* cost  = (const float*)d_in[0];
    const float* feat  = (const float*)d_in[1];
    const float* w_q   = (const float*)d_in[2];
    const float* w_k   = (const float*)d_in[3];
    const float* w_v   = (const float*)d_in[4];
    const float* w_out = (const float*)d_in[5];
    const float* gniw  = (const float*)d_in[6];
    const float* gnib  = (const float*)d_in[7];
    const float* gow   = (const float*)d_in[8];
    const float* gob   = (const float*)d_in[9];
    const float* gamma = (const float*)d_in[10];

    float* ws = (float*)d_ws;
    float* outp = (float*)d_out;

    unsigned short* zb = (unsigned short*)(ws + OFF_ZB);
    unsigned short* qr = (unsigned short*)(ws + OFF_QR);
    float2* part1 = (float2*)(ws + OFF_P1);
    float2* part2 = (float2*)(ws + OFF_P2);
    float2* st1 = (float2*)(ws + OFF_ST1);
    float2* st2 = (float2*)(ws + OFF_ST2);
    float* pkv = ws + OFF_PKV;

    k1_pool<<<dim3(NBLK, Bn), 256, 0, stream>>>(cost, feat, w_q, w_k, w_v, gniw, qr, part1, pkv);
    k_st1<<<Bn, 256, 0, stream>>>(part1, st1);
    k_attn<<<dim3(128, Bn), 256, 0, stream>>>(qr, pkv, w_q, gniw, gnib, st1, w_out, zb);
    k_ystats<<<Bn * Cn * Dn, 256, 0, stream>>>(cost, zb, gamma, part2);
    k_fin2<<<Bn, 256, 0, stream>>>(part2, st2);
    k_final<<<Bn * Cn * Dn, 256, 0, stream>>>(cost, zb, gamma, st2, gow, gob, outp);
}

// Round 9
// 193.785 us; speedup vs baseline: 3.0400x; 1.0436x over previous
//
#include <hip/hip_runtime.h>
#include <hip/hip_fp16.h>

typedef float f4v __attribute__((ext_vector_type(4)));

namespace {
constexpr int Bn = 4, Cn = 32, Dn = 48, Hn = 64, Wn = 128;
constexpr int HQ = 32, WQ = 64;
constexpr int NPB = Dn * HQ * WQ;   // 98304 pooled positions / batch
constexpr int DHW = Dn * Hn * Wn;   // 393216
constexpr int PERB = Cn * DHW;      // 12582912 elements / batch
constexpr int NS = 128, En = 12;
constexpr float EPS = 1e-5f;
constexpr float SQK = 0.2886751345948129f;  // 1/sqrt(12)
constexpr int NBLK = 384;                   // grid.x of k1

// workspace float offsets
constexpr size_t OFF_ZB  = 0;                      // bf16[4*32*98304] -> 6291456 floats
constexpr size_t OFF_QR  = 6291456;                // bf16[4*12*98304] -> 2359296 floats
constexpr size_t OFF_P1  = OFF_QR + 2359296;       // float2[4*384] -> 3072 floats
constexpr size_t OFF_P2  = OFF_P1 + 3072;          // float2[6144] -> 12288 floats
constexpr size_t OFF_PKV = OFF_P2 + 12288;         // 16*128*24 = 49152
constexpr size_t OFF_CB  = OFF_PKV + 49152;        // fp16[4*PERB] -> 25165824 floats
constexpr size_t WS_NEED_FLOATS = OFF_CB + 25165824;
}  // namespace

__device__ inline unsigned short bf16b(float x) {
    unsigned u = __float_as_uint(x);
    return (unsigned short)((u + 0x7fffu + ((u >> 16) & 1u)) >> 16);
}
__device__ inline float b2f(unsigned short h) { return __uint_as_float(((unsigned)h) << 16); }
__device__ inline float bf16_rne(float x) {
    unsigned u = __float_as_uint(x);
    u = (u + 0x7fffu + ((u >> 16) & 1u)) & 0xffff0000u;
    return __uint_as_float(u);
}

// block = 256 threads; reentrant-safe.
__device__ inline float2 block_red2(float s, float ss) {
#pragma unroll
    for (int off = 32; off; off >>= 1) {
        s += __shfl_down(s, off, 64);
        ss += __shfl_down(ss, off, 64);
    }
    __shared__ float red[8];
    int lane = threadIdx.x & 63, w = threadIdx.x >> 6;
    __syncthreads();
    if (!lane) { red[w] = s; red[4 + w] = ss; }
    __syncthreads();
    return make_float2(red[0] + red[1] + red[2] + red[3],
                       red[4] + red[5] + red[6] + red[7]);
}

// ---------- K1: pool + qraw(bf16) + GN-in partial stats + fp16 cost copy + K/V partials ----------
template <bool CB>
__global__ __launch_bounds__(256) void k1_pool(const float* __restrict__ cost,
                                               const float* __restrict__ feat,
                                               const float* __restrict__ w_q,
                                               const float* __restrict__ w_k,
                                               const float* __restrict__ w_v,
                                               const float* __restrict__ gniw,
                                               unsigned short* __restrict__ qr,
                                               float2* __restrict__ part1,
                                               float* __restrict__ pkv,
                                               __half* __restrict__ cb) {
    __shared__ float wqg[En * Cn];
    const int b = blockIdx.y, tid = threadIdx.x;
    for (int i = tid; i < En * Cn; i += 256) wqg[i] = w_q[i] * gniw[i & 31];
    __syncthreads();
    const int n = blockIdx.x * 256 + tid;
    const int d = n >> 11, r = n & 2047, hq = r >> 6, wq = r & 63;
    const size_t ebase = (size_t)b * PERB + (size_t)d * 8192 + (hq * 2) * Wn + wq * 2;
    const float* base = cost + ebase;
    float s = 0.f, ss = 0.f;
    float q[En];
#pragma unroll
    for (int e = 0; e < En; ++e) q[e] = 0.f;
#pragma unroll 4
    for (int c = 0; c < Cn; ++c) {
        const float* src = base + (size_t)c * DHW;
        float2 t0 = *reinterpret_cast<const float2*>(src);
        float2 t1 = *reinterpret_cast<const float2*>(src + Wn);
        if (CB) {
            __half* cd = cb + ebase + (size_t)c * DHW;
            *reinterpret_cast<__half2*>(cd) =
                __halves2half2(__float2half_rn(t0.x), __float2half_rn(t0.y));
            *reinterpret_cast<__half2*>(cd + Wn) =
                __halves2half2(__float2half_rn(t1.x), __float2half_rn(t1.y));
        }
        float ps = t0.x + t0.y + t1.x + t1.y;
        s += ps;
        ss += t0.x * t0.x + t0.y * t0.y + t1.x * t1.x + t1.y * t1.y;
        float pv = 0.25f * ps;
#pragma unroll
        for (int e = 0; e < En; ++e) q[e] += wqg[e * Cn + c] * pv;
    }
#pragma unroll
    for (int e = 0; e < En; ++e) qr[(size_t)(b * En + e) * NPB + n] = bf16b(q[e]);
    float2 rp = block_red2(s, ss);
    if (!tid) part1[b * NBLK + blockIdx.x] = rp;

    // K/V partials: 16 blocks (b==0, x<16). g = x: kb = g>>2 (batch), cg = g&3 (64-ch group)
    if (b == 0 && blockIdx.x < 16 && tid < NS) {
        const int g = blockIdx.x, kb = g >> 2, cg = g & 3, sI = tid;
        float kk[En], vv[En];
#pragma unroll
        for (int e = 0; e < En; ++e) { kk[e] = 0.f; vv[e] = 0.f; }
        for (int ch = 0; ch < 4; ++ch) {
            const int c0 = cg * 64 + ch * 16;
            float f[16];
#pragma unroll
            for (int jj = 0; jj < 16; ++jj) f[jj] = feat[(size_t)(kb * 256 + c0 + jj) * NS + sI];
#pragma unroll
            for (int jj = 0; jj < 16; ++jj) {
                const int c = c0 + jj;
#pragma unroll
                for (int e = 0; e < En; ++e) {
                    kk[e] += w_k[e * 256 + c] * f[jj];
                    vv[e] += w_v[e * 256 + c] * f[jj];
                }
            }
        }
#pragma unroll
        for (int e = 0; e < En; ++e) {
            pkv[((size_t)(g * NS + sI)) * 24 + e] = kk[e];
            pkv[((size_t)(g * NS + sI)) * 24 + 12 + e] = vv[e];
        }
    }
}

// ---------- K2: attention, 3 positions/thread; st1 reduced in prologue ----------
__global__ __launch_bounds__(256) void k_attn(const unsigned short* __restrict__ qr,
                                              const float* __restrict__ pkv,
                                              const float* __restrict__ w_q,
                                              const float* __restrict__ gniw,
                                              const float* __restrict__ gnib,
                                              const float2* __restrict__ part1,
                                              const float* __restrict__ w_out,
                                              unsigned short* __restrict__ zb) {
    __shared__ float Ks[NS * En], Vs[NS * En], WOs[Cn * En], QBs[En];
    __shared__ float kred[2], kscs_sh;
    const int x = blockIdx.x, b = blockIdx.y, tid = threadIdx.x;

    // st1: redundant per-block reduce of part1[b]
    float sP = 0.f, ssP = 0.f;
    for (int i = tid; i < NBLK; i += 256) {
        float2 v = part1[b * NBLK + i];
        sP += v.x; ssP += v.y;
    }
    float2 tP = block_red2(sP, ssP);
    const float mGN = tP.x / (float)PERB;
    const float rsGN = rsqrtf(tP.y / (float)PERB - mGN * mGN + EPS);

    // prologue: combine K/V partials, weights, q-bias
    for (int i = tid; i < NS * En; i += 256) {
        int s = i / En, e = i - s * En;
        size_t base = ((size_t)((b * 4) * NS + s)) * 24 + e;
        Ks[i] = pkv[base] + pkv[base + 3072] + pkv[base + 6144] + pkv[base + 9216];
        Vs[i] = pkv[base + 12] + pkv[base + 3084] + pkv[base + 6156] + pkv[base + 9228];
    }
    for (int i = tid; i < Cn * En; i += 256) WOs[i] = w_out[i];
    if (tid < En) {
        float acc = 0.f;
        for (int c = 0; c < Cn; ++c)
            acc += w_q[tid * Cn + c] * (gnib[c] - mGN * rsGN * gniw[c]);
        QBs[tid] = SQK * acc;
    }
    __syncthreads();
    if (tid < NS) {
        float n2 = 0.f;
#pragma unroll
        for (int e = 0; e < En; ++e) { float k = Ks[tid * En + e]; n2 += k * k; }
#pragma unroll
        for (int off = 32; off; off >>= 1) n2 = fmaxf(n2, __shfl_down(n2, off, 64));
        if (!(tid & 63)) kred[tid >> 6] = n2;
    }
    __syncthreads();
    if (!tid) kscs_sh = sqrtf(fmaxf(kred[0], kred[1]));
    __syncthreads();
    const float kscs = kscs_sh;
    const float qsc = rsGN * SQK;

    const int nbase = x * 768 + tid;  // positions nbase, nbase+256, nbase+512

    f4v q[3][3];
    float ub[3];
#pragma unroll
    for (int p = 0; p < 3; ++p) {
        const int n = nbase + 256 * p;
        float qn2 = 0.f;
#pragma unroll
        for (int v = 0; v < 3; ++v) {
            f4v t;
#pragma unroll
            for (int u = 0; u < 4; ++u) {
                int e = v * 4 + u;
                float qe = qsc * b2f(qr[(size_t)(b * En + e) * NPB + n]) + QBs[e];
                t[u] = qe;
                qn2 += qe * qe;
            }
            q[p][v] = t;
        }
        ub[p] = sqrtf(qn2) * kscs;  // Cauchy-Schwarz >= max logit
    }

    f4v o0[3], o1[3], o2[3];
    float l[3];
#pragma unroll
    for (int p = 0; p < 3; ++p) {
        o0[p] = (f4v)(0.f); o1[p] = (f4v)(0.f); o2[p] = (f4v)(0.f);
        l[p] = 0.f;
    }
    const f4v* K4 = (const f4v*)Ks;
    const f4v* V4 = (const f4v*)Vs;
    for (int s = 0; s < NS; ++s) {
        f4v k0 = K4[s * 3], k1 = K4[s * 3 + 1], k2 = K4[s * 3 + 2];
        f4v v0 = V4[s * 3], v1 = V4[s * 3 + 1], v2 = V4[s * 3 + 2];
#pragma unroll
        for (int p = 0; p < 3; ++p) {
            f4v d4 = q[p][0] * k0 + q[p][1] * k1 + q[p][2] * k2;
            float dot = (d4.x + d4.y) + (d4.z + d4.w);
            float pe = __expf(dot - ub[p]);
            l[p] += pe;
            o0[p] += pe * v0; o1[p] += pe * v1; o2[p] += pe * v2;
        }
    }

    const f4v* WO4 = (const f4v*)WOs;
#pragma unroll
    for (int p = 0; p < 3; ++p) {
        const float inv = 1.0f / l[p];
        const int n = nbase + 256 * p;
        for (int c = 0; c < Cn; ++c) {
            f4v z4 = WO4[c * 3] * o0[p] + WO4[c * 3 + 1] * o1[p] + WO4[c * 3 + 2] * o2[p];
            float z = ((z4.x + z4.y) + (z4.z + z4.w)) * inv;
            zb[(size_t)(b * Cn + c) * NPB + n] = bf16b(z);
        }
    }
}

// upsample helper: y values for quad qd of a slice, given LDS z-rows
__device__ inline void up_quad(int qd, const unsigned short* __restrict__ zs,
                               float g, float (&u4)[4]) {
    int h = qd >> 5, w4 = (qd & 31) << 2;
    int h0 = (h - 1) >> 1;
    float wh0 = (h & 1) ? 0.75f : 0.25f;
    int h1 = h0 + 1;
    h0 = h0 < 0 ? 0 : h0; h1 = h1 > HQ - 1 ? HQ - 1 : h1;
    const unsigned short* r0 = zs + h0 * WQ;
    const unsigned short* r1 = zs + h1 * WQ;
#pragma unroll
    for (int p = 0; p < 4; ++p) {
        int w = w4 + p;
        int w0 = (w - 1) >> 1;
        float ww0 = (w & 1) ? 0.75f : 0.25f;
        int w1 = w0 + 1;
        w0 = w0 < 0 ? 0 : w0; w1 = w1 > WQ - 1 ? WQ - 1 : w1;
        float u = wh0 * (ww0 * b2f(r0[w0]) + (1.f - ww0) * b2f(r0[w1])) +
                  (1.f - wh0) * (ww0 * b2f(r1[w0]) + (1.f - ww0) * b2f(r1[w1]));
        u4[p] = g * bf16_rne(u);
    }
}

// ---------- K3: y-stats; one block per (b,c,d) slice ----------
template <bool CB>
__global__ __launch_bounds__(256) void k_ystats(const float* __restrict__ cost,
                                                const __half* __restrict__ cb,
                                                const unsigned short* __restrict__ zb,
                                                const float* __restrict__ gamma_p,
                                                float2* __restrict__ part2) {
    const int blk = blockIdx.x;  // ((b*32+c)*48+d)
    __shared__ unsigned short zs[HQ * WQ];
    const int tid = threadIdx.x;
    {
        const unsigned int* zsrc = (const unsigned int*)(zb + (size_t)blk * 2048);
        for (int i = tid; i < 1024; i += 256) ((unsigned int*)zs)[i] = zsrc[i];
    }
    __syncthreads();
    const float g = gamma_p[0];
    float s = 0.f, ss = 0.f;
#pragma unroll
    for (int k = 0; k < 8; ++k) {
        int qd = tid + 256 * k;
        float u4[4];
        up_quad(qd, zs, g, u4);
        float cvv[4];
        if (CB) {
            uint2 pk = *reinterpret_cast<const uint2*>(cb + (size_t)blk * 8192 + qd * 4);
            float2 f01 = __half22float2(*reinterpret_cast<__half2*>(&pk.x));
            float2 f23 = __half22float2(*reinterpret_cast<__half2*>(&pk.y));
            cvv[0] = f01.x; cvv[1] = f01.y; cvv[2] = f23.x; cvv[3] = f23.y;
        } else {
            f4v cv = ((const f4v*)(cost + (size_t)blk * 8192))[qd];
            cvv[0] = cv.x; cvv[1] = cv.y; cvv[2] = cv.z; cvv[3] = cv.w;
        }
#pragma unroll
        for (int p = 0; p < 4; ++p) {
            float y = cvv[p] + u4[p];
            s += y; ss += y * y;
        }
    }
    float2 rp = block_red2(s, ss);
    if (!tid) part2[blk] = rp;
}

// ---------- K4: final GroupNorm (stats2 reduced in prologue), nontemporal store ----------
template <bool CB>
__global__ __launch_bounds__(256) void k_final(const float* __restrict__ cost,
                                               const __half* __restrict__ cb,
                                               const unsigned short* __restrict__ zb,
                                               const float* __restrict__ gamma_p,
                                               const float2* __restrict__ part2,
                                               const float* __restrict__ gow,
                                               const float* __restrict__ gob,
                                               float* __restrict__ out) {
    const int blk = blockIdx.x;
    const int b = blk / (Cn * Dn);
    const int c = (blk / Dn) % Cn;
    const int tid = threadIdx.x;

    // stats2: redundant per-block reduce
    float sP = 0.f, ssP = 0.f;
    for (int i = tid; i < Cn * Dn; i += 256) {
        float2 v = part2[b * Cn * Dn + i];
        sP += v.x; ssP += v.y;
    }
    float2 tP = block_red2(sP, ssP);
    const float m = tP.x / (float)PERB;
    const float rs = rsqrtf(tP.y / (float)PERB - m * m + EPS);

    __shared__ unsigned short zs[HQ * WQ];
    {
        const unsigned int* zsrc = (const unsigned int*)(zb + (size_t)blk * 2048);
        for (int i = tid; i < 1024; i += 256) ((unsigned int*)zs)[i] = zsrc[i];
    }
    __syncthreads();
    const float g = gamma_p[0];
    const float sc = rs * gow[c], bi = gob[c];
    f4v* oq = (f4v*)(out + (size_t)blk * 8192);
#pragma unroll
    for (int k = 0; k < 8; ++k) {
        int qd = tid + 256 * k;
        float u4[4];
        up_quad(qd, zs, g, u4);
        float cvv[4];
        if (CB) {
            uint2 pk = *reinterpret_cast<const uint2*>(cb + (size_t)blk * 8192 + qd * 4);
            float2 f01 = __half22float2(*reinterpret_cast<__half2*>(&pk.x));
            float2 f23 = __half22float2(*reinterpret_cast<__half2*>(&pk.y));
            cvv[0] = f01.x; cvv[1] = f01.y; cvv[2] = f23.x; cvv[3] = f23.y;
        } else {
            f4v cv = ((const f4v*)(cost + (size_t)blk * 8192))[qd];
            cvv[0] = cv.x; cvv[1] = cv.y; cvv[2] = cv.z; cvv[3] = cv.w;
        }
        f4v ov;
#pragma unroll
        for (int p = 0; p < 4; ++p) {
            float y = cvv[p] + u4[p];
            ov[p] = (y - m) * sc + bi;
        }
        __builtin_nontemporal_store(ov, oq + qd);
    }
}

extern "C" void kernel_launch(void* const* d_in, const int* in_sizes, int n_in,
                              void* d_out, int out_size, void* d_ws, size_t ws_size,
                              hipStream_t stream) {
    const float* cost  = (const float*)d_in[0];
    const float* feat  = (const float*)d_in[1];
    const float* w_q   = (const float*)d_in[2];
    const float* w_k   = (const float*)d_in[3];
    const float* w_v   = (const float*)d_in[4];
    const float* w_out = (const float*)d_in[5];
    const float* gniw  = (const float*)d_in[6];
    const float* gnib  = (const float*)d_in[7];
    const float* gow   = (const float*)d_in[8];
    const float* gob   = (const float*)d_in[9];
    const float* gamma = (const float*)d_in[10];

    float* ws = (float*)d_ws;
    float* outp = (float*)d_out;

    unsigned short* zb = (unsigned short*)(ws + OFF_ZB);
    unsigned short* qr = (unsigned short*)(ws + OFF_QR);
    float2* part1 = (float2*)(ws + OFF_P1);
    float2* part2 = (float2*)(ws + OFF_P2);
    float* pkv = ws + OFF_PKV;
    __half* cb = (__half*)(ws + OFF_CB);

    const bool useCB = ws_size >= WS_NEED_FLOATS * sizeof(float);

    if (useCB) {
        k1_pool<true><<<dim3(NBLK, Bn), 256, 0, stream>>>(cost, feat, w_q, w_k, w_v, gniw,
                                                          qr, part1, pkv, cb);
        k_attn<<<dim3(128, Bn), 256, 0, stream>>>(qr, pkv, w_q, gniw, gnib, part1, w_out, zb);
        k_ystats<true><<<Bn * Cn * Dn, 256, 0, stream>>>(cost, cb, zb, gamma, part2);
        k_final<true><<<Bn * Cn * Dn, 256, 0, stream>>>(cost, cb, zb, gamma, part2, gow, gob, outp);
    } else {
        k1_pool<false><<<dim3(NBLK, Bn), 256, 0, stream>>>(cost, feat, w_q, w_k, w_v, gniw,
                                                           qr, part1, pkv, cb);
        k_attn<<<dim3(128, Bn), 256, 0, stream>>>(qr, pkv, w_q, gniw, gnib, part1, w_out, zb);
        k_ystats<false><<<Bn * Cn * Dn, 256, 0, stream>>>(cost, cb, zb, gamma, part2);
        k_final<false><<<Bn * Cn * Dn, 256, 0, stream>>>(cost, cb, zb, gamma, part2, gow, gob, outp);
    }
}

// Round 10
// 193.014 us; speedup vs baseline: 3.0522x; 1.0040x over previous
//
#include <hip/hip_runtime.h>
#include <hip/hip_fp16.h>

typedef float f4v __attribute__((ext_vector_type(4)));

namespace {
constexpr int Bn = 4, Cn = 32, Dn = 48, Hn = 64, Wn = 128;
constexpr int HQ = 32, WQ = 64;
constexpr int NPB = Dn * HQ * WQ;   // 98304 pooled positions / batch
constexpr int DHW = Dn * Hn * Wn;   // 393216
constexpr int PERB = Cn * DHW;      // 12582912 elements / batch
constexpr int NS = 128, En = 12;
constexpr float EPS = 1e-5f;
constexpr float SQK = 0.2886751345948129f;  // 1/sqrt(12)
constexpr int NB1 = 192;                    // grid.x of k1 (512 pooled cells/block)

// workspace float offsets
constexpr size_t OFF_ZB  = 0;                      // bf16[4*32*98304] -> 6291456 floats
constexpr size_t OFF_QR  = 6291456;                // bf16[4*12*98304] -> 2359296 floats
constexpr size_t OFF_P1  = OFF_QR + 2359296;       // float2[4*192] -> 1536 floats
constexpr size_t OFF_P2  = OFF_P1 + 1536;          // float2[6144] -> 12288 floats
constexpr size_t OFF_PKV = OFF_P2 + 12288;         // 16*128*24 = 49152
constexpr size_t OFF_CB  = OFF_PKV + 49152;        // fp16[4*PERB] -> 25165824 floats
constexpr size_t WS_NEED_FLOATS = OFF_CB + 25165824;
}  // namespace

__device__ inline unsigned short bf16b(float x) {
    unsigned u = __float_as_uint(x);
    return (unsigned short)((u + 0x7fffu + ((u >> 16) & 1u)) >> 16);
}
__device__ inline float b2f(unsigned short h) { return __uint_as_float(((unsigned)h) << 16); }
__device__ inline float bf16_rne(float x) {
    unsigned u = __float_as_uint(x);
    u = (u + 0x7fffu + ((u >> 16) & 1u)) & 0xffff0000u;
    return __uint_as_float(u);
}

// block = 256 threads; reentrant-safe.
__device__ inline float2 block_red2(float s, float ss) {
#pragma unroll
    for (int off = 32; off; off >>= 1) {
        s += __shfl_down(s, off, 64);
        ss += __shfl_down(ss, off, 64);
    }
    __shared__ float red[8];
    int lane = threadIdx.x & 63, w = threadIdx.x >> 6;
    __syncthreads();
    if (!lane) { red[w] = s; red[4 + w] = ss; }
    __syncthreads();
    return make_float2(red[0] + red[1] + red[2] + red[3],
                       red[4] + red[5] + red[6] + red[7]);
}

// ---------- K1: pool (2 cells/thread) + qraw + stats + fp16 cost copy + K/V partials ----------
template <bool CB>
__global__ __launch_bounds__(256) void k1_pool(const float* __restrict__ cost,
                                               const float* __restrict__ feat,
                                               const float* __restrict__ w_q,
                                               const float* __restrict__ w_k,
                                               const float* __restrict__ w_v,
                                               const float* __restrict__ gniw,
                                               unsigned short* __restrict__ qr,
                                               float2* __restrict__ part1,
                                               float* __restrict__ pkv,
                                               __half* __restrict__ cb) {
    __shared__ float wqg[En * Cn];
    const int b = blockIdx.y, tid = threadIdx.x;
    for (int i = tid; i < En * Cn; i += 256) wqg[i] = w_q[i] * gniw[i & 31];
    __syncthreads();
    const int np = blockIdx.x * 512 + tid * 2;  // even pooled index; pair (np, np+1)
    const int d = np >> 11, r = np & 2047, hq = r >> 6, wq = r & 63;  // wq even
    const size_t fbase = (size_t)b * PERB + (size_t)d * 8192 + (size_t)(hq * 2) * Wn + wq * 2;
    float s = 0.f, ss = 0.f;
    float q0[En], q1[En];
#pragma unroll
    for (int e = 0; e < En; ++e) { q0[e] = 0.f; q1[e] = 0.f; }
#pragma unroll 4
    for (int c = 0; c < Cn; ++c) {
        const size_t off = fbase + (size_t)c * DHW;
        f4v t0, t1;
        if (CB) {
            t0 = __builtin_nontemporal_load((const f4v*)(cost + off));
            t1 = __builtin_nontemporal_load((const f4v*)(cost + off + Wn));
            __half2 h01 = __halves2half2(__float2half_rn(t0.x), __float2half_rn(t0.y));
            __half2 h23 = __halves2half2(__float2half_rn(t0.z), __float2half_rn(t0.w));
            __half2 g01 = __halves2half2(__float2half_rn(t1.x), __float2half_rn(t1.y));
            __half2 g23 = __halves2half2(__float2half_rn(t1.z), __float2half_rn(t1.w));
            uint2 pk0 = make_uint2(*(unsigned*)&h01, *(unsigned*)&h23);
            uint2 pk1 = make_uint2(*(unsigned*)&g01, *(unsigned*)&g23);
            *reinterpret_cast<uint2*>(cb + off) = pk0;
            *reinterpret_cast<uint2*>(cb + off + Wn) = pk1;
        } else {
            t0 = *reinterpret_cast<const f4v*>(cost + off);
            t1 = *reinterpret_cast<const f4v*>(cost + off + Wn);
        }
        float p0 = t0.x + t0.y + t1.x + t1.y;
        float p1 = t0.z + t0.w + t1.z + t1.w;
        s += p0 + p1;
        ss += t0.x * t0.x + t0.y * t0.y + t0.z * t0.z + t0.w * t0.w +
              t1.x * t1.x + t1.y * t1.y + t1.z * t1.z + t1.w * t1.w;
        p0 *= 0.25f; p1 *= 0.25f;
#pragma unroll
        for (int e = 0; e < En; ++e) {
            q0[e] += wqg[e * Cn + c] * p0;
            q1[e] += wqg[e * Cn + c] * p1;
        }
    }
#pragma unroll
    for (int e = 0; e < En; ++e) {
        unsigned pk = (unsigned)bf16b(q0[e]) | ((unsigned)bf16b(q1[e]) << 16);
        *reinterpret_cast<unsigned*>(qr + (size_t)(b * En + e) * NPB + np) = pk;
    }
    float2 rp = block_red2(s, ss);
    if (!tid) part1[b * NB1 + blockIdx.x] = rp;

    // K/V partials: 16 blocks (b==0, x<16). g = x: kb = g>>2 (batch), cg = g&3 (64-ch group)
    if (b == 0 && blockIdx.x < 16 && tid < NS) {
        const int g = blockIdx.x, kb = g >> 2, cg = g & 3, sI = tid;
        float kk[En], vv[En];
#pragma unroll
        for (int e = 0; e < En; ++e) { kk[e] = 0.f; vv[e] = 0.f; }
        for (int ch = 0; ch < 4; ++ch) {
            const int c0 = cg * 64 + ch * 16;
            float f[16];
#pragma unroll
            for (int jj = 0; jj < 16; ++jj) f[jj] = feat[(size_t)(kb * 256 + c0 + jj) * NS + sI];
#pragma unroll
            for (int jj = 0; jj < 16; ++jj) {
                const int c = c0 + jj;
#pragma unroll
                for (int e = 0; e < En; ++e) {
                    kk[e] += w_k[e * 256 + c] * f[jj];
                    vv[e] += w_v[e * 256 + c] * f[jj];
                }
            }
        }
#pragma unroll
        for (int e = 0; e < En; ++e) {
            pkv[((size_t)(g * NS + sI)) * 24 + e] = kk[e];
            pkv[((size_t)(g * NS + sI)) * 24 + 12 + e] = vv[e];
        }
    }
}

// ---------- K2: attention, 3 positions/thread; st1 reduced in prologue ----------
__global__ __launch_bounds__(256) void k_attn(const unsigned short* __restrict__ qr,
                                              const float* __restrict__ pkv,
                                              const float* __restrict__ w_q,
                                              const float* __restrict__ gniw,
                                              const float* __restrict__ gnib,
                                              const float2* __restrict__ part1,
                                              const float* __restrict__ w_out,
                                              unsigned short* __restrict__ zb) {
    __shared__ float Ks[NS * En], Vs[NS * En], WOs[Cn * En], QBs[En];
    __shared__ float kred[2], kscs_sh;
    const int x = blockIdx.x, b = blockIdx.y, tid = threadIdx.x;

    // st1: redundant per-block reduce of part1[b]
    float sP = 0.f, ssP = 0.f;
    if (tid < NB1) {
        float2 v = part1[b * NB1 + tid];
        sP = v.x; ssP = v.y;
    }
    float2 tP = block_red2(sP, ssP);
    const float mGN = tP.x / (float)PERB;
    const float rsGN = rsqrtf(tP.y / (float)PERB - mGN * mGN + EPS);

    // prologue: combine K/V partials, weights, q-bias
    for (int i = tid; i < NS * En; i += 256) {
        int s = i / En, e = i - s * En;
        size_t base = ((size_t)((b * 4) * NS + s)) * 24 + e;
        Ks[i] = pkv[base] + pkv[base + 3072] + pkv[base + 6144] + pkv[base + 9216];
        Vs[i] = pkv[base + 12] + pkv[base + 3084] + pkv[base + 6156] + pkv[base + 9228];
    }
    for (int i = tid; i < Cn * En; i += 256) WOs[i] = w_out[i];
    if (tid < En) {
        float acc = 0.f;
        for (int c = 0; c < Cn; ++c)
            acc += w_q[tid * Cn + c] * (gnib[c] - mGN * rsGN * gniw[c]);
        QBs[tid] = SQK * acc;
    }
    __syncthreads();
    if (tid < NS) {
        float n2 = 0.f;
#pragma unroll
        for (int e = 0; e < En; ++e) { float k = Ks[tid * En + e]; n2 += k * k; }
#pragma unroll
        for (int off = 32; off; off >>= 1) n2 = fmaxf(n2, __shfl_down(n2, off, 64));
        if (!(tid & 63)) kred[tid >> 6] = n2;
    }
    __syncthreads();
    if (!tid) kscs_sh = sqrtf(fmaxf(kred[0], kred[1]));
    __syncthreads();
    const float kscs = kscs_sh;
    const float qsc = rsGN * SQK;

    const int nbase = x * 768 + tid;  // positions nbase, nbase+256, nbase+512

    f4v q[3][3];
    float ub[3];
#pragma unroll
    for (int p = 0; p < 3; ++p) {
        const int n = nbase + 256 * p;
        float qn2 = 0.f;
#pragma unroll
        for (int v = 0; v < 3; ++v) {
            f4v t;
#pragma unroll
            for (int u = 0; u < 4; ++u) {
                int e = v * 4 + u;
                float qe = qsc * b2f(qr[(size_t)(b * En + e) * NPB + n]) + QBs[e];
                t[u] = qe;
                qn2 += qe * qe;
            }
            q[p][v] = t;
        }
        ub[p] = sqrtf(qn2) * kscs;  // Cauchy-Schwarz >= max logit
    }

    f4v o0[3], o1[3], o2[3];
    float l[3];
#pragma unroll
    for (int p = 0; p < 3; ++p) {
        o0[p] = (f4v)(0.f); o1[p] = (f4v)(0.f); o2[p] = (f4v)(0.f);
        l[p] = 0.f;
    }
    const f4v* K4 = (const f4v*)Ks;
    const f4v* V4 = (const f4v*)Vs;
    for (int s = 0; s < NS; ++s) {
        f4v k0 = K4[s * 3], k1 = K4[s * 3 + 1], k2 = K4[s * 3 + 2];
        f4v v0 = V4[s * 3], v1 = V4[s * 3 + 1], v2 = V4[s * 3 + 2];
#pragma unroll
        for (int p = 0; p < 3; ++p) {
            f4v d4 = q[p][0] * k0 + q[p][1] * k1 + q[p][2] * k2;
            float dot = (d4.x + d4.y) + (d4.z + d4.w);
            float pe = __expf(dot - ub[p]);
            l[p] += pe;
            o0[p] += pe * v0; o1[p] += pe * v1; o2[p] += pe * v2;
        }
    }

    const f4v* WO4 = (const f4v*)WOs;
#pragma unroll
    for (int p = 0; p < 3; ++p) {
        const float inv = 1.0f / l[p];
        const int n = nbase + 256 * p;
        for (int c = 0; c < Cn; ++c) {
            f4v z4 = WO4[c * 3] * o0[p] + WO4[c * 3 + 1] * o1[p] + WO4[c * 3 + 2] * o2[p];
            float z = ((z4.x + z4.y) + (z4.z + z4.w)) * inv;
            zb[(size_t)(b * Cn + c) * NPB + n] = bf16b(z);
        }
    }
}

// upsample helper: u (already *gamma*) values for quad qd of a slice, given LDS z-rows
__device__ inline void up_quad(int qd, const unsigned short* __restrict__ zs,
                               float g, float (&u4)[4]) {
    int h = qd >> 5, w4 = (qd & 31) << 2;
    int h0 = (h - 1) >> 1;
    float wh0 = (h & 1) ? 0.75f : 0.25f;
    int h1 = h0 + 1;
    h0 = h0 < 0 ? 0 : h0; h1 = h1 > HQ - 1 ? HQ - 1 : h1;
    const unsigned short* r0 = zs + h0 * WQ;
    const unsigned short* r1 = zs + h1 * WQ;
#pragma unroll
    for (int p = 0; p < 4; ++p) {
        int w = w4 + p;
        int w0 = (w - 1) >> 1;
        float ww0 = (w & 1) ? 0.75f : 0.25f;
        int w1 = w0 + 1;
        w0 = w0 < 0 ? 0 : w0; w1 = w1 > WQ - 1 ? WQ - 1 : w1;
        float u = wh0 * (ww0 * b2f(r0[w0]) + (1.f - ww0) * b2f(r0[w1])) +
                  (1.f - wh0) * (ww0 * b2f(r1[w0]) + (1.f - ww0) * b2f(r1[w1]));
        u4[p] = g * bf16_rne(u);
    }
}

// ---------- K3: y-stats; one block per (b,c,d) slice ----------
template <bool CB>
__global__ __launch_bounds__(256) void k_ystats(const float* __restrict__ cost,
                                                const __half* __restrict__ cb,
                                                const unsigned short* __restrict__ zb,
                                                const float* __restrict__ gamma_p,
                                                float2* __restrict__ part2) {
    const int blk = blockIdx.x;  // ((b*32+c)*48+d)
    __shared__ unsigned short zs[HQ * WQ];
    const int tid = threadIdx.x;
    {
        const unsigned int* zsrc = (const unsigned int*)(zb + (size_t)blk * 2048);
        for (int i = tid; i < 1024; i += 256) ((unsigned int*)zs)[i] = zsrc[i];
    }
    __syncthreads();
    const float g = gamma_p[0];
    float s = 0.f, ss = 0.f;
#pragma unroll
    for (int k = 0; k < 8; ++k) {
        int qd = tid + 256 * k;
        float u4[4];
        up_quad(qd, zs, g, u4);
        float cvv[4];
        if (CB) {
            uint2 pk = *reinterpret_cast<const uint2*>(cb + (size_t)blk * 8192 + qd * 4);
            float2 f01 = __half22float2(*reinterpret_cast<__half2*>(&pk.x));
            float2 f23 = __half22float2(*reinterpret_cast<__half2*>(&pk.y));
            cvv[0] = f01.x; cvv[1] = f01.y; cvv[2] = f23.x; cvv[3] = f23.y;
        } else {
            f4v cv = ((const f4v*)(cost + (size_t)blk * 8192))[qd];
            cvv[0] = cv.x; cvv[1] = cv.y; cvv[2] = cv.z; cvv[3] = cv.w;
        }
#pragma unroll
        for (int p = 0; p < 4; ++p) {
            float y = cvv[p] + u4[p];
            s += y; ss += y * y;
        }
    }
    float2 rp = block_red2(s, ss);
    if (!tid) part2[blk] = rp;
}

// ---------- K4: final GroupNorm (stats2 reduced in prologue), nontemporal store ----------
template <bool CB>
__global__ __launch_bounds__(256) void k_final(const float* __restrict__ cost,
                                               const __half* __restrict__ cb,
                                               const unsigned short* __restrict__ zb,
                                               const float* __restrict__ gamma_p,
                                               const float2* __restrict__ part2,
                                               const float* __restrict__ gow,
                                               const float* __restrict__ gob,
                                               float* __restrict__ out) {
    const int blk = blockIdx.x;
    const int b = blk / (Cn * Dn);
    const int c = (blk / Dn) % Cn;
    const int tid = threadIdx.x;

    // stats2: redundant per-block reduce
    float sP = 0.f, ssP = 0.f;
    for (int i = tid; i < Cn * Dn; i += 256) {
        float2 v = part2[b * Cn * Dn + i];
        sP += v.x; ssP += v.y;
    }
    float2 tP = block_red2(sP, ssP);
    const float m = tP.x / (float)PERB;
    const float rs = rsqrtf(tP.y / (float)PERB - m * m + EPS);

    __shared__ unsigned short zs[HQ * WQ];
    {
        const unsigned int* zsrc = (const unsigned int*)(zb + (size_t)blk * 2048);
        for (int i = tid; i < 1024; i += 256) ((unsigned int*)zs)[i] = zsrc[i];
    }
    __syncthreads();
    const float g = gamma_p[0];
    const float sc = rs * gow[c], bi = gob[c];
    f4v* oq = (f4v*)(out + (size_t)blk * 8192);
#pragma unroll
    for (int k = 0; k < 8; ++k) {
        int qd = tid + 256 * k;
        float u4[4];
        up_quad(qd, zs, g, u4);
        float cvv[4];
        if (CB) {
            uint2 pk = *reinterpret_cast<const uint2*>(cb + (size_t)blk * 8192 + qd * 4);
            float2 f01 = __half22float2(*reinterpret_cast<__half2*>(&pk.x));
            float2 f23 = __half22float2(*reinterpret_cast<__half2*>(&pk.y));
            cvv[0] = f01.x; cvv[1] = f01.y; cvv[2] = f23.x; cvv[3] = f23.y;
        } else {
            f4v cv = ((const f4v*)(cost + (size_t)blk * 8192))[qd];
            cvv[0] = cv.x; cvv[1] = cv.y; cvv[2] = cv.z; cvv[3] = cv.w;
        }
        f4v ov;
#pragma unroll
        for (int p = 0; p < 4; ++p) {
            float y = cvv[p] + u4[p];
            ov[p] = (y - m) * sc + bi;
        }
        __builtin_nontemporal_store(ov, oq + qd);
    }
}

extern "C" void kernel_launch(void* const* d_in, const int* in_sizes, int n_in,
                              void* d_out, int out_size, void* d_ws, size_t ws_size,
                              hipStream_t stream) {
    const float* cost  = (const float*)d_in[0];
    const float* feat  = (const float*)d_in[1];
    const float* w_q   = (const float*)d_in[2];
    const float* w_k   = (const float*)d_in[3];
    const float* w_v   = (const float*)d_in[4];
    const float* w_out = (const float*)d_in[5];
    const float* gniw  = (const float*)d_in[6];
    const float* gnib  = (const float*)d_in[7];
    const float* gow   = (const float*)d_in[8];
    const float* gob   = (const float*)d_in[9];
    const float* gamma = (const float*)d_in[10];

    float* ws = (float*)d_ws;
    float* outp = (float*)d_out;

    unsigned short* zb = (unsigned short*)(ws + OFF_ZB);
    unsigned short* qr = (unsigned short*)(ws + OFF_QR);
    float2* part1 = (float2*)(ws + OFF_P1);
    float2* part2 = (float2*)(ws + OFF_P2);
    float* pkv = ws + OFF_PKV;
    __half* cb = (__half*)(ws + OFF_CB);

    const bool useCB = ws_size >= WS_NEED_FLOATS * sizeof(float);

    if (useCB) {
        k1_pool<true><<<dim3(NB1, Bn), 256, 0, stream>>>(cost, feat, w_q, w_k, w_v, gniw,
                                                         qr, part1, pkv, cb);
        k_attn<<<dim3(128, Bn), 256, 0, stream>>>(qr, pkv, w_q, gniw, gnib, part1, w_out, zb);
        k_ystats<true><<<Bn * Cn * Dn, 256, 0, stream>>>(cost, cb, zb, gamma, part2);
        k_final<true><<<Bn * Cn * Dn, 256, 0, stream>>>(cost, cb, zb, gamma, part2, gow, gob, outp);
    } else {
        k1_pool<false><<<dim3(NB1, Bn), 256, 0, stream>>>(cost, feat, w_q, w_k, w_v, gniw,
                                                          qr, part1, pkv, cb);
        k_attn<<<dim3(128, Bn), 256, 0, stream>>>(qr, pkv, w_q, gniw, gnib, part1, w_out, zb);
        k_ystats<false><<<Bn * Cn * Dn, 256, 0, stream>>>(cost, cb, zb, gamma, part2);
        k_final<false><<<Bn * Cn * Dn, 256, 0, stream>>>(cost, cb, zb, gamma, part2, gow, gob, outp);
    }
}